// Round 12
// baseline (380.068 us; speedup 1.0000x reference)
//
#include <hip/hip_runtime.h>
#include <hip/hip_bf16.h>

#define S 16
#define B 8
#define H 16
#define DH 64
#define D 1024
#define HD 1024          // H*DH
#define LC 8192
#define LMAX (LC + S)    // 8208
#define NCH 32           // L-chunks per (b,hg)
#define CHT 256          // t rows per chunk
#define TILE 16          // rows staged per iteration
#define NT (CHT / TILE)  // 16
#define BUFS 8320        // shorts per LDS buffer (K 4096 + V 4224)

typedef __attribute__((ext_vector_type(4))) float f4;
typedef __attribute__((ext_vector_type(4))) short s4v;
typedef __attribute__((ext_vector_type(8))) short s8v;

__device__ inline short bfs(float f) {
    __hip_bfloat16 h = __float2bfloat16(f);   // RNE; pairs fuse to cvt_pk
    return __builtin_bit_cast(short, h);
}
__device__ inline s4v pack4(float a, float b, float c, float d) {
    s4v r; r[0] = bfs(a); r[1] = bfs(b); r[2] = bfs(c); r[3] = bfs(d); return r;
}

// ---- QKV projection: 8 rows/block (halves W re-reads vs 4), scalar-uniform x
// grid = 16 rowgroups * 12 (mat,chunk); block = 256
__global__ __launch_bounds__(256) void proj_qkv(const float* __restrict__ x,
        const float* __restrict__ Wq, const float* __restrict__ Wk,
        const float* __restrict__ Wv,
        float* __restrict__ q_ws, float* __restrict__ newk, float* __restrict__ newv,
        float* __restrict__ res)
{
    int bx = blockIdx.x;
    int rg  = bx / 12;
    int rem = bx % 12;
    int mat = rem >> 2, chunk = rem & 3;
    int o = chunk * 256 + threadIdx.x;
    const float* W  = (mat == 0) ? Wq : ((mat == 1) ? Wk : Wv);
    const float* xr = x + (size_t)rg * 8 * D;

    float acc[8];
    #pragma unroll
    for (int i = 0; i < 8; ++i) acc[i] = 0.f;
    #pragma unroll 16
    for (int d = 0; d < D; ++d) {
        float w = W[(size_t)d * HD + o];
        #pragma unroll
        for (int i = 0; i < 8; ++i) acc[i] += xr[(size_t)i * D + d] * w;
    }
    #pragma unroll
    for (int i = 0; i < 8; ++i) {
        int row = rg * 8 + i;
        int s = row >> 3, b = row & 7;
        if (mat == 0) {
            q_ws[(size_t)row * HD + o] = acc[i];
            res[(size_t)row * D + o] = 0.f;      // zero res for combine_proj atomics
        } else {
            float* dst = (mat == 1) ? newk : newv;
            dst[(size_t)((LC + s) * B + b) * HD + o] = acc[i];
        }
    }
}

// ---- fused cache-copy + MFMA flash attention ------------------------------
// grid = B*4*NCH; TILE=16 rows x [4 heads x 64 dh] 1KB-contiguous. Wave wid owns
// head hg*4+wid. LDS double-buffered: ONE barrier/iter; compute(t) from buf[cur],
// then stage(t+1) -> buf[nxt] (loads issued a full iteration earlier, T14).
__global__ __launch_bounds__(256, 3) void attn_fused(const float* __restrict__ q_ws,
        const float* __restrict__ cache_k, const float* __restrict__ cache_v,
        float* __restrict__ newk, float* __restrict__ newv,
        float* __restrict__ m_part, float* __restrict__ l_part,
        float* __restrict__ pv_part)
{
    extern __shared__ short smem_s[];
    short* K0 = smem_s;                // buf0: K [16][256] swz (8KB)
    short* V0 = smem_s + 4096;         // buf0: V 4 heads x 1056 (8.25KB)
    short* K1 = smem_s + BUFS;
    short* V1 = smem_s + BUFS + 4096;

    int bx = blockIdx.x;
    int chunk = bx & 31;
    int hgb = bx >> 5;
    int hg = hgb & 3, b = hgb >> 2;
    int tid = threadIdx.x, l = tid & 63, wid = tid >> 6;
    int g = l >> 4, c16 = l & 15;
    int h = hg * 4 + wid;
    int rrb = tid >> 6, ch = tid & 63;    // stage: row-base, 16B-chunk in 1KB row
    int w = ch >> 4, cc = ch & 15;

    // Q fragments for head h
    s8v qf[2];
    {
        const float* qp = q_ws + ((size_t)(c16 * B + b)) * HD + h * DH + g * 8;
        #pragma unroll
        for (int sl = 0; sl < 2; ++sl) {
            float4 qa = *(const float4*)(qp + sl * 32);
            float4 qb = *(const float4*)(qp + sl * 32 + 4);
            s8v q;
            q[0] = bfs(qa.x * 0.125f); q[1] = bfs(qa.y * 0.125f);
            q[2] = bfs(qa.z * 0.125f); q[3] = bfs(qa.w * 0.125f);
            q[4] = bfs(qb.x * 0.125f); q[5] = bfs(qb.y * 0.125f);
            q[6] = bfs(qb.z * 0.125f); q[7] = bfs(qb.w * 0.125f);
            qf[sl] = q;
        }
    }

    float m_prev = -1e30f, l_acc = 0.f;
    f4 acc[4] = {{0,0,0,0},{0,0,0,0},{0,0,0,0},{0,0,0,0}};

    int t0base = chunk * CHT;
    int sw = (c16 & 7) << 3;
    size_t cbase = (size_t)b * 1024 + hg * 256 + ch * 4;

    f4 kb[2][4], vb[2][4];

    auto load_tile = [&](int t0, f4 (&kg)[4], f4 (&vg)[4]) {
        #pragma unroll
        for (int gg = 0; gg < 4; ++gg) {
            size_t off = ((size_t)(t0 + rrb + 4 * gg)) * 8192 + cbase;
            kg[gg] = __builtin_nontemporal_load((const f4*)(cache_k + off));
            vg[gg] = __builtin_nontemporal_load((const f4*)(cache_v + off));
        }
    };
    auto stage_tile = [&](short* Kb, short* Vb, int t0, f4 (&kg)[4], f4 (&vg)[4]) {
        #pragma unroll
        for (int gg = 0; gg < 4; ++gg) {
            int rr = rrb + 4 * gg;
            size_t off = ((size_t)(t0 + rr)) * 8192 + cbase;
            __builtin_nontemporal_store(kg[gg], (f4*)(newk + off));
            __builtin_nontemporal_store(vg[gg], (f4*)(newv + off));
            int kidx = rr * 256 + w * 64 + ((cc * 4) ^ ((rr & 7) << 3));
            *(s4v*)(Kb + kidx) = pack4(kg[gg][0], kg[gg][1], kg[gg][2], kg[gg][3]);
            int vidx = w * 1056 + (cc >> 2) * 264 + (rr >> 2) * 64 + (rr & 3) * 16 + (cc & 3) * 4;
            *(s4v*)(Vb + vidx) = pack4(vg[gg][0], vg[gg][1], vg[gg][2], vg[gg][3]);
        }
    };
    auto compute_tile = [&](short* Kb, short* Vb, bool causal) {
        __builtin_amdgcn_s_setprio(1);
        f4 d0 = {0,0,0,0};
        #pragma unroll
        for (int sl = 0; sl < 2; ++sl) {
            int col = (sl * 32 + g * 8) ^ sw;
            s8v k0 = *(const s8v*)(Kb + c16 * 256 + wid * 64 + col);
            d0 = __builtin_amdgcn_mfma_f32_16x16x32_bf16(k0, qf[sl], d0, 0, 0, 0);
        }
        if (causal) {
            #pragma unroll
            for (int r = 0; r < 4; ++r)
                if (4 * g + r > c16) d0[r] = -1e30f;   // t > s
        }
        float hm = fmaxf(fmaxf(d0[0], d0[1]), fmaxf(d0[2], d0[3]));
        hm = fmaxf(hm, __shfl_xor(hm, 16));
        hm = fmaxf(hm, __shfl_xor(hm, 32));
        float mn = fmaxf(m_prev, hm);
        float sf = __expf(m_prev - mn);
        m_prev = mn;
        f4 p0;
        #pragma unroll
        for (int r = 0; r < 4; ++r) p0[r] = __expf(d0[r] - mn);
        float rs = (p0[0] + p0[1]) + (p0[2] + p0[3]);
        rs += __shfl_xor(rs, 16);
        rs += __shfl_xor(rs, 32);
        l_acc = l_acc * sf + rs;
        #pragma unroll
        for (int dd = 0; dd < 4; ++dd) acc[dd] *= sf;

        s4v pb0 = pack4(p0[0], p0[1], p0[2], p0[3]);
        unsigned vb_ = (unsigned)(uintptr_t)Vb + (unsigned)wid * 2112u;
        s4v vfr[4];
        #pragma unroll
        for (int dd = 0; dd < 4; ++dd) {
            unsigned adr = vb_ + 2u * (unsigned)(dd * 264 + g * 64 + c16);
            asm volatile("ds_read_b64_tr_b16 %0, %1" : "=v"(vfr[dd]) : "v"(adr));
        }
        asm volatile("s_waitcnt lgkmcnt(0)" ::: "memory");
        __builtin_amdgcn_sched_barrier(0);
        #pragma unroll
        for (int dd = 0; dd < 4; ++dd)
            acc[dd] = __builtin_amdgcn_mfma_f32_16x16x16bf16_1k(vfr[dd], pb0, acc[dd], 0, 0, 0);
        __builtin_amdgcn_s_setprio(0);
    };

    // prologue: tile0 -> buf0 (staged), tile1 loads in flight
    load_tile(t0base, kb[0], vb[0]);
    stage_tile(K0, V0, t0base, kb[0], vb[0]);
    load_tile(t0base + TILE, kb[1], vb[1]);
    asm volatile("s_waitcnt lgkmcnt(0)" ::: "memory");
    __builtin_amdgcn_s_barrier();
    __builtin_amdgcn_sched_barrier(0);

    #pragma unroll
    for (int it = 0; it < NT; ++it) {
        const int cur = it & 1, nxt = cur ^ 1;
        short* Kc = cur ? K1 : K0;
        short* Vc = cur ? V1 : V0;
        short* Kn = cur ? K0 : K1;
        short* Vn = cur ? V0 : V1;

        // compute tile it from buf[cur] (no vmem dependence — starts immediately)
        compute_tile(Kc, Vc, false);

        // stage tile it+1 into buf[nxt] (loads issued one iteration ago),
        // then issue loads for tile it+2
        if (it + 1 < NT) {
            stage_tile(Kn, Vn, t0base + (it + 1) * TILE, kb[nxt], vb[nxt]);
            if (it + 2 < NT)
                load_tile(t0base + (it + 2) * TILE, kb[cur], vb[cur]);
        }
        // single barrier per iter (lgkm only; global loads/stores stay in flight)
        asm volatile("s_waitcnt lgkmcnt(0)" ::: "memory");
        __builtin_amdgcn_s_barrier();
        __builtin_amdgcn_sched_barrier(0);
    }

    // tail: 16 new rows (t = LC..LC+15), causal-masked, buf0
    if (chunk == NCH - 1) {
        __syncthreads();
        #pragma unroll
        for (int q = 0; q < 4; ++q) {
            int idx = tid + q * 256;
            int rr = idx >> 6, c2 = idx & 63;
            int w2 = c2 >> 4, cc2 = c2 & 15;
            size_t off = ((size_t)(LC + rr)) * 8192 + (size_t)b * 1024 + hg * 256 + c2 * 4;
            float4 k4 = *(const float4*)(newk + off);
            float4 v4 = *(const float4*)(newv + off);
            int kidx = rr * 256 + w2 * 64 + ((cc2 * 4) ^ ((rr & 7) << 3));
            *(s4v*)(K0 + kidx) = pack4(k4.x, k4.y, k4.z, k4.w);
            int vidx = w2 * 1056 + (cc2 >> 2) * 264 + (rr >> 2) * 64 + (rr & 3) * 16 + (cc2 & 3) * 4;
            *(s4v*)(V0 + vidx) = pack4(v4.x, v4.y, v4.z, v4.w);
        }
        __syncthreads();
        compute_tile(K0, V0, true);
    }

    // emit per-wave (= per-head) partials
    int pi = ((b * 16 + h) * NCH) + chunk;
    #pragma unroll
    for (int dd = 0; dd < 4; ++dd)
        #pragma unroll
        for (int r = 0; r < 4; ++r)
            pv_part[((size_t)pi * 64 + dd * 16 + g * 4 + r) * 16 + c16] = acc[dd][r];
    if (l < 16) {
        m_part[pi * 16 + l] = m_prev;
        l_part[pi * 16 + l] = l_acc;
    }
}

// ---- fused combine + output projection ------------------------------------
// grid = B*H*4 (bh*4 + oc), block = 256; atomicAdd into res (zeroed by proj_qkv)
__global__ __launch_bounds__(256) void combine_proj(const float* __restrict__ m_part,
        const float* __restrict__ l_part, const float* __restrict__ pv_part,
        const float* __restrict__ Wo, float* __restrict__ res)
{
    __shared__ float wexp[NCH][16];
    __shared__ float Ls[16];
    __shared__ float cds[64][16];          // ctx^T [d][s] for this (b,h)
    int bx = blockIdx.x;
    int oc = bx & 3, bh = bx >> 2;
    int h = bh & 15, b = bh >> 4;
    int tid = threadIdx.x;

    if (tid < 16) {
        int s = tid;
        float M = -1e30f;
        #pragma unroll
        for (int c = 0; c < NCH; ++c) M = fmaxf(M, m_part[(bh * NCH + c) * 16 + s]);
        float L = 0.f;
        #pragma unroll
        for (int c = 0; c < NCH; ++c) {
            float e = __expf(m_part[(bh * NCH + c) * 16 + s] - M);
            wexp[c][s] = e;
            L += e * l_part[(bh * NCH + c) * 16 + s];
        }
        Ls[s] = L;
    }
    __syncthreads();
    #pragma unroll
    for (int k = 0; k < 4; ++k) {
        int idx = tid + k * 256;
        int d = idx >> 4, s = idx & 15;
        float v = 0.f;
        #pragma unroll
        for (int c = 0; c < NCH; ++c)
            v += wexp[c][s] * pv_part[((size_t)(bh * NCH + c) * 64 + d) * 16 + s];
        cds[d][s] = v / Ls[s];
    }
    __syncthreads();

    int o = oc * 256 + tid;
    float acc[16];
    #pragma unroll
    for (int s = 0; s < 16; ++s) acc[s] = 0.f;
    #pragma unroll 8
    for (int d = 0; d < 64; ++d) {
        float wv = Wo[(size_t)(h * 64 + d) * D + o];
        #pragma unroll
        for (int q = 0; q < 4; ++q) {
            f4 cq = *(const f4*)&cds[d][q * 4];   // broadcast reads
            acc[q * 4 + 0] += cq[0] * wv;
            acc[q * 4 + 1] += cq[1] * wv;
            acc[q * 4 + 2] += cq[2] * wv;
            acc[q * 4 + 3] += cq[3] * wv;
        }
    }
    #pragma unroll
    for (int s = 0; s < 16; ++s)
        atomicAdd(res + (size_t)(s * B + b) * D + o, acc[s]);
}

extern "C" void kernel_launch(void* const* d_in, const int* in_sizes, int n_in,
                              void* d_out, int out_size, void* d_ws, size_t ws_size,
                              hipStream_t stream)
{
    const float* x  = (const float*)d_in[0];
    const float* ck = (const float*)d_in[1];
    const float* cv = (const float*)d_in[2];
    const float* Wq = (const float*)d_in[3];
    const float* Wk = (const float*)d_in[4];
    const float* Wv = (const float*)d_in[5];
    const float* Wo = (const float*)d_in[6];

    float* out  = (float*)d_out;
    float* res  = out;                                   // (S,B,D)
    float* newk = out + (size_t)S * B * D;               // (L,B,H,DH)
    float* newv = newk + (size_t)LMAX * B * H * DH;

    float* q_ws    = (float*)d_ws;                               // 131072 f
    float* ctx     = q_ws + (size_t)S * B * HD;                  // (layout kept)
    float* m_part  = ctx + (size_t)S * B * HD;                   // 4096*16 f
    float* l_part  = m_part + (size_t)B * H * NCH * S;           // 4096*16 f
    float* pv_part = l_part + (size_t)B * H * NCH * S;           // 4096*1024 f

    size_t smem = (size_t)BUFS * 2 * 2;                          // 33280 B

    hipLaunchKernelGGL(proj_qkv, dim3(16 * 12), dim3(256), 0, stream,
                       x, Wq, Wk, Wv, q_ws, newk, newv, res);
    hipLaunchKernelGGL(attn_fused, dim3(B * 4 * NCH), dim3(256), smem, stream,
                       q_ws, ck, cv, newk, newv, m_part, l_part, pv_part);
    hipLaunchKernelGGL(combine_proj, dim3(B * H * 4), dim3(256), 0, stream,
                       m_part, l_part, pv_part, Wo, res);
}

// Round 13
// 365.613 us; speedup vs baseline: 1.0395x; 1.0395x over previous
//
#include <hip/hip_runtime.h>
#include <hip/hip_bf16.h>

#define S 16
#define B 8
#define H 16
#define DH 64
#define D 1024
#define HD 1024          // H*DH
#define LC 8192
#define LMAX (LC + S)    // 8208
#define NCH 32           // L-chunks per (b,hg)
#define CHT 256          // t rows per chunk
#define TILE 16          // rows staged per iteration
#define NT (CHT / TILE)  // 16

typedef __attribute__((ext_vector_type(4))) float f4;
typedef __attribute__((ext_vector_type(4))) short s4v;
typedef __attribute__((ext_vector_type(8))) short s8v;

__device__ inline short bfs(float f) {
    __hip_bfloat16 h = __float2bfloat16(f);   // RNE; pairs fuse to cvt_pk
    return __builtin_bit_cast(short, h);
}
__device__ inline s4v pack4(float a, float b, float c, float d) {
    s4v r; r[0] = bfs(a); r[1] = bfs(b); r[2] = bfs(c); r[3] = bfs(d); return r;
}

// ---- QKV projection: 8 rows/block, 128-wide output chunks ------------------
// grid = 16 rowgroups * 3 mats * 8 chunks = 384 blocks; block = 128 threads.
// W traffic = 192 MB (vs 384 MB at 4 rows/block); W loads 512B/wave coalesced.
__global__ __launch_bounds__(128) void proj_qkv(const float* __restrict__ x,
        const float* __restrict__ Wq, const float* __restrict__ Wk,
        const float* __restrict__ Wv,
        float* __restrict__ q_ws, float* __restrict__ newk, float* __restrict__ newv,
        float* __restrict__ res)
{
    int bx = blockIdx.x;
    int rg  = bx / 24;
    int rem = bx % 24;
    int mat = rem >> 3, chunk = rem & 7;
    int o = chunk * 128 + threadIdx.x;
    const float* W  = (mat == 0) ? Wq : ((mat == 1) ? Wk : Wv);
    const float* xr = x + (size_t)rg * 8 * D;

    float acc[8];
    #pragma unroll
    for (int i = 0; i < 8; ++i) acc[i] = 0.f;
    #pragma unroll 16
    for (int d = 0; d < D; ++d) {
        float w = W[(size_t)d * HD + o];
        #pragma unroll
        for (int i = 0; i < 8; ++i) acc[i] += xr[(size_t)i * D + d] * w;
    }
    #pragma unroll
    for (int i = 0; i < 8; ++i) {
        int row = rg * 8 + i;
        int s = row >> 3, b = row & 7;
        if (mat == 0) {
            q_ws[(size_t)row * HD + o] = acc[i];
            res[(size_t)row * D + o] = 0.f;      // zero res for combine_proj atomics
        } else {
            float* dst = (mat == 1) ? newk : newv;
            dst[(size_t)((LC + s) * B + b) * HD + o] = acc[i];
        }
    }
}

// ---- fused cache-copy + MFMA flash attention (R11, proven) ----------------
// grid = B*4*NCH: chunk (0..31) fastest, then hg (0..3), b (0..7).
// TILE=16 rows x [4 heads x 64 dh] = 1KB-contiguous rows. Wave wid owns head hg*4+wid.
// Register double-buffer: tile it+1's loads issued a full iteration before use.
// CRITICAL ORDER: loads issued BEFORE stage's stores each iteration, so vmcnt
// waits on loads never drain older stores (R12 lesson).
__global__ __launch_bounds__(256, 4) void attn_fused(const float* __restrict__ q_ws,
        const float* __restrict__ cache_k, const float* __restrict__ cache_v,
        float* __restrict__ newk, float* __restrict__ newv,
        float* __restrict__ m_part, float* __restrict__ l_part,
        float* __restrict__ pv_part)
{
    extern __shared__ char smem[];
    short* Ksp = (short*)smem;            // [16][256] bf16, XOR-swz per 64-elem head slice (8KB)
    short* Vp  = Ksp + TILE * 256;        // 4 heads x (4 dd x 264) subtiled V (8448B)

    int bx = blockIdx.x;
    int chunk = bx & 31;
    int hgb = bx >> 5;
    int hg = hgb & 3, b = hgb >> 2;
    int tid = threadIdx.x, l = tid & 63, wid = tid >> 6;
    int g = l >> 4, c16 = l & 15;
    int h = hg * 4 + wid;
    int rrb = tid >> 6, ch = tid & 63;    // stage: row-base, 16B-chunk in 1KB row
    int w = ch >> 4, cc = ch & 15;
    unsigned vbase = (unsigned)(uintptr_t)Vp + (unsigned)wid * 2112u;

    // Q fragments for head h
    s8v qf[2];
    {
        const float* qp = q_ws + ((size_t)(c16 * B + b)) * HD + h * DH + g * 8;
        #pragma unroll
        for (int sl = 0; sl < 2; ++sl) {
            float4 qa = *(const float4*)(qp + sl * 32);
            float4 qb = *(const float4*)(qp + sl * 32 + 4);
            s8v q;
            q[0] = bfs(qa.x * 0.125f); q[1] = bfs(qa.y * 0.125f);
            q[2] = bfs(qa.z * 0.125f); q[3] = bfs(qa.w * 0.125f);
            q[4] = bfs(qb.x * 0.125f); q[5] = bfs(qb.y * 0.125f);
            q[6] = bfs(qb.z * 0.125f); q[7] = bfs(qb.w * 0.125f);
            qf[sl] = q;
        }
    }

    float m_prev = -1e30f, l_acc = 0.f;
    f4 acc[4] = {{0,0,0,0},{0,0,0,0},{0,0,0,0},{0,0,0,0}};

    int t0base = chunk * CHT;
    int sw = (c16 & 7) << 3;
    size_t cbase = (size_t)b * 1024 + hg * 256 + ch * 4;

    // prologue: prefetch tile 0
    f4 kb[2][4], vb[2][4];
    #pragma unroll
    for (int gg = 0; gg < 4; ++gg) {
        size_t off = ((size_t)(t0base + rrb + 4 * gg)) * 8192 + cbase;
        kb[0][gg] = __builtin_nontemporal_load((const f4*)(cache_k + off));
        vb[0][gg] = __builtin_nontemporal_load((const f4*)(cache_v + off));
    }

    #pragma unroll
    for (int it = 0; it < NT; ++it) {
        const int cur = it & 1, nxt = cur ^ 1;
        int t0 = t0base + it * TILE;

        // issue next tile's loads FIRST (stay in flight across barriers + compute)
        if (it + 1 < NT) {
            #pragma unroll
            for (int gg = 0; gg < 4; ++gg) {
                size_t off = ((size_t)(t0 + TILE + rrb + 4 * gg)) * 8192 + cbase;
                kb[nxt][gg] = __builtin_nontemporal_load((const f4*)(cache_k + off));
                vb[nxt][gg] = __builtin_nontemporal_load((const f4*)(cache_v + off));
            }
        }
        // barrier 1: previous tile's LDS readers done (lgkm only)
        asm volatile("s_waitcnt lgkmcnt(0)" ::: "memory");
        __builtin_amdgcn_s_barrier();
        __builtin_amdgcn_sched_barrier(0);

        // stage cur tile: fp32 copy out, bf16 into LDS (K swz, V subtiled)
        #pragma unroll
        for (int gg = 0; gg < 4; ++gg) {
            int rr = rrb + 4 * gg;
            size_t off = ((size_t)(t0 + rr)) * 8192 + cbase;
            __builtin_nontemporal_store(kb[cur][gg], (f4*)(newk + off));
            __builtin_nontemporal_store(vb[cur][gg], (f4*)(newv + off));
            int kidx = rr * 256 + w * 64 + ((cc * 4) ^ ((rr & 7) << 3));
            *(s4v*)(Ksp + kidx) = pack4(kb[cur][gg][0], kb[cur][gg][1], kb[cur][gg][2], kb[cur][gg][3]);
            int vidx = w * 1056 + (cc >> 2) * 264 + (rr >> 2) * 64 + (rr & 3) * 16 + (cc & 3) * 4;
            *(s4v*)(Vp + vidx) = pack4(vb[cur][gg][0], vb[cur][gg][1], vb[cur][gg][2], vb[cur][gg][3]);
        }
        // barrier 2: staging ds_writes visible (lgkm only; stores/loads in flight)
        asm volatile("s_waitcnt lgkmcnt(0)" ::: "memory");
        __builtin_amdgcn_s_barrier();
        __builtin_amdgcn_sched_barrier(0);

        // QK^T: D[t][s] for this head's 16 rows
        f4 d0 = {0,0,0,0};
        #pragma unroll
        for (int sl = 0; sl < 2; ++sl) {
            int col = (sl * 32 + g * 8) ^ sw;
            s8v k0 = *(const s8v*)(Ksp + c16 * 256 + wid * 64 + col);
            d0 = __builtin_amdgcn_mfma_f32_16x16x32_bf16(k0, qf[sl], d0, 0, 0, 0);
        }
        // online softmax (per-lane state for s = c16)
        float hm = fmaxf(fmaxf(d0[0], d0[1]), fmaxf(d0[2], d0[3]));
        hm = fmaxf(hm, __shfl_xor(hm, 16));
        hm = fmaxf(hm, __shfl_xor(hm, 32));
        float mn = fmaxf(m_prev, hm);
        float sf = __expf(m_prev - mn);
        m_prev = mn;
        f4 p0;
        #pragma unroll
        for (int r = 0; r < 4; ++r) p0[r] = __expf(d0[r] - mn);
        float rs = (p0[0] + p0[1]) + (p0[2] + p0[3]);
        rs += __shfl_xor(rs, 16);
        rs += __shfl_xor(rs, 32);
        l_acc = l_acc * sf + rs;
        #pragma unroll
        for (int dd = 0; dd < 4; ++dd) acc[dd] *= sf;

        // PV: A = V^T via tr-reads, B = P
        s4v pb0 = pack4(p0[0], p0[1], p0[2], p0[3]);
        s4v vfr[4];
        #pragma unroll
        for (int dd = 0; dd < 4; ++dd) {
            unsigned adr = vbase + 2u * (unsigned)(dd * 264 + g * 64 + c16);
            asm volatile("ds_read_b64_tr_b16 %0, %1" : "=v"(vfr[dd]) : "v"(adr));
        }
        asm volatile("s_waitcnt lgkmcnt(0)" ::: "memory");
        __builtin_amdgcn_sched_barrier(0);
        #pragma unroll
        for (int dd = 0; dd < 4; ++dd)
            acc[dd] = __builtin_amdgcn_mfma_f32_16x16x16bf16_1k(vfr[dd], pb0, acc[dd], 0, 0, 0);
    }

    // tail: 16 new rows (t = LC..LC+15), causal-masked
    if (chunk == NCH - 1) {
        __syncthreads();
        #pragma unroll
        for (int q = 0; q < 4; ++q) {
            int idx = tid + q * 256;
            int rr = idx >> 6, c2 = idx & 63;
            int w2 = c2 >> 4, cc2 = c2 & 15;
            size_t off = ((size_t)(LC + rr)) * 8192 + (size_t)b * 1024 + hg * 256 + c2 * 4;
            float4 k4 = *(const float4*)(newk + off);
            float4 v4 = *(const float4*)(newv + off);
            int kidx = rr * 256 + w2 * 64 + ((cc2 * 4) ^ ((rr & 7) << 3));
            *(s4v*)(Ksp + kidx) = pack4(k4.x, k4.y, k4.z, k4.w);
            int vidx = w2 * 1056 + (cc2 >> 2) * 264 + (rr >> 2) * 64 + (rr & 3) * 16 + (cc2 & 3) * 4;
            *(s4v*)(Vp + vidx) = pack4(v4.x, v4.y, v4.z, v4.w);
        }
        __syncthreads();
        f4 d0 = {0,0,0,0};
        #pragma unroll
        for (int sl = 0; sl < 2; ++sl) {
            int col = (sl * 32 + g * 8) ^ sw;
            s8v k0 = *(const s8v*)(Ksp + c16 * 256 + wid * 64 + col);
            d0 = __builtin_amdgcn_mfma_f32_16x16x32_bf16(k0, qf[sl], d0, 0, 0, 0);
        }
        #pragma unroll
        for (int r = 0; r < 4; ++r)
            if (4 * g + r > c16) d0[r] = -1e30f;   // causal: t > s
        float hm = fmaxf(fmaxf(d0[0], d0[1]), fmaxf(d0[2], d0[3]));
        hm = fmaxf(hm, __shfl_xor(hm, 16));
        hm = fmaxf(hm, __shfl_xor(hm, 32));
        float mn = fmaxf(m_prev, hm);
        float sf = __expf(m_prev - mn);
        m_prev = mn;
        f4 p0;
        #pragma unroll
        for (int r = 0; r < 4; ++r) p0[r] = __expf(d0[r] - mn);
        float rs = (p0[0] + p0[1]) + (p0[2] + p0[3]);
        rs += __shfl_xor(rs, 16);
        rs += __shfl_xor(rs, 32);
        l_acc = l_acc * sf + rs;
        #pragma unroll
        for (int dd = 0; dd < 4; ++dd) acc[dd] *= sf;
        s4v pb0 = pack4(p0[0], p0[1], p0[2], p0[3]);
        s4v vfr[4];
        #pragma unroll
        for (int dd = 0; dd < 4; ++dd) {
            unsigned adr = vbase + 2u * (unsigned)(dd * 264 + g * 64 + c16);
            asm volatile("ds_read_b64_tr_b16 %0, %1" : "=v"(vfr[dd]) : "v"(adr));
        }
        asm volatile("s_waitcnt lgkmcnt(0)" ::: "memory");
        __builtin_amdgcn_sched_barrier(0);
        #pragma unroll
        for (int dd = 0; dd < 4; ++dd)
            acc[dd] = __builtin_amdgcn_mfma_f32_16x16x16bf16_1k(vfr[dd], pb0, acc[dd], 0, 0, 0);
    }

    // emit per-wave (= per-head) partials
    int pi = ((b * 16 + h) * NCH) + chunk;
    #pragma unroll
    for (int dd = 0; dd < 4; ++dd)
        #pragma unroll
        for (int r = 0; r < 4; ++r)
            pv_part[((size_t)pi * 64 + dd * 16 + g * 4 + r) * 16 + c16] = acc[dd][r];
    if (l < 16) {
        m_part[pi * 16 + l] = m_prev;
        l_part[pi * 16 + l] = l_acc;
    }
}

// ---- fused combine + output projection (R11, proven) ----------------------
// grid = B*H*4 (bh*4 + oc), block = 256; atomicAdd into res (zeroed by proj_qkv)
__global__ __launch_bounds__(256) void combine_proj(const float* __restrict__ m_part,
        const float* __restrict__ l_part, const float* __restrict__ pv_part,
        const float* __restrict__ Wo, float* __restrict__ res)
{
    __shared__ float wexp[NCH][16];
    __shared__ float Ls[16];
    __shared__ float cds[64][16];          // ctx^T [d][s] for this (b,h)
    int bx = blockIdx.x;
    int oc = bx & 3, bh = bx >> 2;
    int h = bh & 15, b = bh >> 4;
    int tid = threadIdx.x;

    if (tid < 16) {
        int s = tid;
        float M = -1e30f;
        #pragma unroll
        for (int c = 0; c < NCH; ++c) M = fmaxf(M, m_part[(bh * NCH + c) * 16 + s]);
        float L = 0.f;
        #pragma unroll
        for (int c = 0; c < NCH; ++c) {
            float e = __expf(m_part[(bh * NCH + c) * 16 + s] - M);
            wexp[c][s] = e;
            L += e * l_part[(bh * NCH + c) * 16 + s];
        }
        Ls[s] = L;
    }
    __syncthreads();
    #pragma unroll
    for (int k = 0; k < 4; ++k) {
        int idx = tid + k * 256;
        int d = idx >> 4, s = idx & 15;
        float v = 0.f;
        #pragma unroll
        for (int c = 0; c < NCH; ++c)
            v += wexp[c][s] * pv_part[((size_t)(bh * NCH + c) * 64 + d) * 16 + s];
        cds[d][s] = v / Ls[s];
    }
    __syncthreads();

    int o = oc * 256 + tid;
    float acc[16];
    #pragma unroll
    for (int s = 0; s < 16; ++s) acc[s] = 0.f;
    #pragma unroll 8
    for (int d = 0; d < 64; ++d) {
        float wv = Wo[(size_t)(h * 64 + d) * D + o];
        #pragma unroll
        for (int q = 0; q < 4; ++q) {
            f4 cq = *(const f4*)&cds[d][q * 4];   // broadcast reads
            acc[q * 4 + 0] += cq[0] * wv;
            acc[q * 4 + 1] += cq[1] * wv;
            acc[q * 4 + 2] += cq[2] * wv;
            acc[q * 4 + 3] += cq[3] * wv;
        }
    }
    #pragma unroll
    for (int s = 0; s < 16; ++s)
        atomicAdd(res + (size_t)(s * B + b) * D + o, acc[s]);
}

extern "C" void kernel_launch(void* const* d_in, const int* in_sizes, int n_in,
                              void* d_out, int out_size, void* d_ws, size_t ws_size,
                              hipStream_t stream)
{
    const float* x  = (const float*)d_in[0];
    const float* ck = (const float*)d_in[1];
    const float* cv = (const float*)d_in[2];
    const float* Wq = (const float*)d_in[3];
    const float* Wk = (const float*)d_in[4];
    const float* Wv = (const float*)d_in[5];
    const float* Wo = (const float*)d_in[6];

    float* out  = (float*)d_out;
    float* res  = out;                                   // (S,B,D)
    float* newk = out + (size_t)S * B * D;               // (L,B,H,DH)
    float* newv = newk + (size_t)LMAX * B * H * DH;

    float* q_ws    = (float*)d_ws;                               // 131072 f
    float* ctx     = q_ws + (size_t)S * B * HD;                  // (layout kept)
    float* m_part  = ctx + (size_t)S * B * HD;                   // 4096*16 f
    float* l_part  = m_part + (size_t)B * H * NCH * S;           // 4096*16 f
    float* pv_part = l_part + (size_t)B * H * NCH * S;           // 4096*1024 f

    size_t smem = (size_t)(TILE * 256 + 4 * 1056) * 2;           // 16640 B

    hipLaunchKernelGGL(proj_qkv, dim3(16 * 24), dim3(128), 0, stream,
                       x, Wq, Wk, Wv, q_ws, newk, newv, res);
    hipLaunchKernelGGL(attn_fused, dim3(B * 4 * NCH), dim3(256), smem, stream,
                       q_ws, ck, cv, newk, newv, m_part, l_part, pv_part);
    hipLaunchKernelGGL(combine_proj, dim3(B * H * 4), dim3(256), 0, stream,
                       m_part, l_part, pv_part, Wo, res);
}